// Round 11
// baseline (978.192 us; speedup 1.0000x reference)
//
#include <hip/hip_runtime.h>
#include <hip/hip_bf16.h>

// DCell forward, bf16-MFMA. Round-10 resubmit (two infra failures; code unchanged):
// dispatch-count reduction (20 -> 13).
//  1 prep          : pack_x (x read once -> ain0/ain1 bf16) ∪ cvt_w_all (W4..W1)
//                    ∪ zero fold-counters
//  2 gemm_small s4 (+fused col stats + last-block fold -> ss)
//  3 bn_tanh_head_vec s4
//  4 gemm_small s3 (+fold)      5 bn_tanh_head_vec s3
//  6 gemm_small s2 (+fold)      7 bn_tanh_head s2 (wave, -> ain1)
//  8 gemm_split<64> s1 (BK=32 dbuf, XCD-swizzled 1D grid)
//  9 reduce_fold_cvt s1 (split-K reduce+bias+h+stats+fold ∪ cvt_w0)
// 10 bn_tanh_head s1 (-> ain0)
// 11 gemm_split<128> s0 (dbuf, swizzled)
// 12 reduce_fold s0            13 bn_tanh_head s0 (no act store)
// Last-block fold: producers __threadfence() + atomicAdd(cnt); the final block
// folds its chunk partials -> per-col scale/shift (no spin — deadlock-free).
// Stage cfg (T,I,O,C,Gs): s4(256,16,20,0,16) s3(64,144,20,80,64)
//  s2(16,336,77,80,256) s1(4,1332,308,308,1024) s0(1,5328,1229,1232,4096)

#define BDIM 2048
#define OUTW 341

typedef __attribute__((ext_vector_type(8))) short short8;
typedef __attribute__((ext_vector_type(4))) float float4v;

static __device__ __forceinline__ unsigned short f2bf(float f) {
    union { float f; unsigned u; } c{f};
    unsigned r = c.u + 0x7FFF + ((c.u >> 16) & 1);  // RNE
    return (unsigned short)(r >> 16);
}
static __device__ __forceinline__ float bf2f(unsigned short s) {
    union { unsigned u; float f; } c{(unsigned)s << 16};
    return c.f;
}

static __device__ __forceinline__ float fast_tanh(float x) {
    float ax = __builtin_fabsf(x);
    float e  = __builtin_amdgcn_exp2f(ax * 2.8853900817779268f);  // e^{2|x|}
    float r  = 1.f - 2.f * __builtin_amdgcn_rcpf(e + 1.f);
    return __builtin_copysignf(r, x);
}

// async global->LDS, 16B/lane: wave-uniform base + lane*16.
static __device__ __forceinline__ void stage16(const void* g, void* ldsBase, int lane) {
#if __has_builtin(__builtin_amdgcn_global_load_lds)
    __builtin_amdgcn_global_load_lds(
        (const __attribute__((address_space(1))) unsigned int*)(uintptr_t)g,
        (__attribute__((address_space(3))) unsigned int*)(unsigned int)(uintptr_t)ldsBase,
        16, 0, 0);
#else
    *(uint4*)((char*)ldsBase + lane * 16) = *(const uint4*)g;
#endif
}

// ---- W[t][I][O] fp32 -> WbT[t][Npad][Kpad] bf16 transpose core ----
static __device__ __forceinline__ void cvt_w_body(const float* Wt, unsigned short* dst,
                                                  int I, int O, int Npad, int Kpad,
                                                  int i0, int o0, int tid) {
    __shared__ unsigned short tile[32][33];
    const int c = tid & 31, r0 = tid >> 5;
    #pragma unroll
    for (int rr = 0; rr < 4; rr++) {
        int i = i0 + r0 + rr * 8, o = o0 + c;
        float v = (i < I && o < O) ? Wt[(size_t)i * O + o] : 0.f;
        tile[r0 + rr * 8][c] = f2bf(v);
    }
    __syncthreads();
    #pragma unroll
    for (int rr = 0; rr < 4; rr++) {
        int o = o0 + r0 + rr * 8, k = i0 + c;
        if (o < Npad) dst[(size_t)o * Kpad + k] = tile[c][r0 + rr * 8];
    }
}

// ---- prep: pack_x ∪ cvt_w_all(W4..W1) ∪ zero counters ----
__global__ __launch_bounds__(256) void prep(const float* __restrict__ x,
                                            unsigned short* __restrict__ ain0,
                                            unsigned short* __restrict__ ain1,
                                            const float* __restrict__ W4,
                                            const float* __restrict__ W3,
                                            const float* __restrict__ W2,
                                            const float* __restrict__ W1,
                                            unsigned short* __restrict__ wbt,
                                            int* __restrict__ cnt) {
    const int bid = blockIdx.x;
    if (bid < 4288) {                         // pack_x region
        const int MAIN = BDIM * 512;          // 8-float units
        int i = bid * 256 + threadIdx.x;
        if (i < MAIN) {
            int b = i >> 9, j = i & 511;
            const float* xp = x + (size_t)b * 4096 + j * 8;
            float4 lo = *(const float4*)xp, hi = *(const float4*)(xp + 4);
            union { unsigned short u[8]; uint4 v4; uint2 v2[2]; } t;
            t.u[0] = f2bf(lo.x); t.u[1] = f2bf(lo.y); t.u[2] = f2bf(lo.z); t.u[3] = f2bf(lo.w);
            t.u[4] = f2bf(hi.x); t.u[5] = f2bf(hi.y); t.u[6] = f2bf(hi.z); t.u[7] = f2bf(hi.w);
            *(uint4*)(ain0 + (size_t)b * 5376 + 1232 + j * 8) = t.v4;
            int gi = j * 8, tt = gi >> 10, u = gi & 1023;
            unsigned short* d1 = ain1 + (size_t)b * 5376 + tt * 1344 + 308 + u;
            *(uint2*)d1 = t.v2[0];
            *(uint2*)(d1 + 4) = t.v2[1];
            return;
        }
        int zi = i - MAIN;
        const int ZU = BDIM * 12;
        if (zi < ZU) {
            int b = zi / 12, u = zi % 12;
            *(uint2*)(ain0 + (size_t)b * 5376 + 5328 + u * 4) = make_uint2(0u, 0u);
        } else if (zi < 2 * ZU) {
            zi -= ZU;
            int b = zi / 12, u = zi % 12, tt = u / 3, k = u % 3;
            *(uint2*)(ain1 + (size_t)b * 5376 + tt * 1344 + 1332 + k * 4) = make_uint2(0u, 0u);
        }
        return;
    }
    if (bid < 7184) {                         // cvt_w_all region
        int b2 = bid - 4288;
        const float* W; unsigned short* dst;
        int I, O, Npad, Kpad, gx, gy, local;
        if (b2 < 256)       { W = W4; dst = wbt;           I = 16;   O = 20;  Npad = 20;  Kpad = 32;   gx = 1;  gy = 1;  local = b2; }
        else if (b2 < 640)  { W = W3; dst = wbt + 163840;  I = 144;  O = 20;  Npad = 20;  Kpad = 192;  gx = 6;  gy = 1;  local = b2 - 256; }
        else if (b2 < 1216) { W = W2; dst = wbt + 409600;  I = 336;  O = 77;  Npad = 77;  Kpad = 384;  gx = 12; gy = 3;  local = b2 - 640; }
        else                { W = W1; dst = wbt + 882688;  I = 1332; O = 308; Npad = 320; Kpad = 1344; gx = 42; gy = 10; local = b2 - 1216; }
        int per = gx * gy;
        int t = local / per, rem = local % per;
        int by = rem / gx, bx = rem % gx;
        cvt_w_body(W + (size_t)t * I * O, dst + (size_t)t * Npad * Kpad,
                   I, O, Npad, Kpad, bx * 32, by * 32, threadIdx.x);
        return;
    }
    for (int i = threadIdx.x; i < 376; i += 256) cnt[i] = 0;   // fold counters
}

// ---- small-stage GEMM + fused col stats + last-block fold -> scale/shift ----
template <int BN, int BK>
__global__ __launch_bounds__(256) void gemm_small(
    const unsigned short* __restrict__ actb,  // [B][T*C] bf16 (null if C==0)
    const unsigned short* __restrict__ xg,    // bf16 x copy, row stride 5376
    const unsigned short* __restrict__ WbT,   // [T][O][Kpad] bf16
    const float* __restrict__ bias,
    unsigned short* __restrict__ h,           // [B][hstride]
    float* __restrict__ sp,                   // [32][2*TO] col-sum partials
    int* __restrict__ cnt,                    // [T] fold counters
    const float* __restrict__ g, const float* __restrict__ bb,
    float* __restrict__ ss,                   // [2*TO] scale/shift out
    int T, int I, int O, int C, int Gs, int Kpad, int hstride, int TO, int nPerT)
{
    const int t  = blockIdx.z;
    const int b0 = blockIdx.y * 64;
    const int o0 = blockIdx.x * BN;
    const int tid = threadIdx.x;
    const int lane = tid & 63;
    const int w = tid >> 6;
    const int l15 = lane & 15;
    const int quad = lane >> 4;

    constexpr int NF = BN / 32;
    const int wm = (w & 1) * 32;
    const int wn = (w >> 1) * (BN / 2);

    __shared__ __align__(16) unsigned short As[64][BK + 8];
    __shared__ __align__(16) unsigned short Bs[BN][BK + 8];
    __shared__ float ldsS[2][BN], ldsS2[2][BN];
    __shared__ int lastFlag;

    float4v acc[2][NF];
    #pragma unroll
    for (int a = 0; a < 2; a++)
        #pragma unroll
        for (int b = 0; b < NF; b++)
            acc[a][b] = (float4v){0.f, 0.f, 0.f, 0.f};

    constexpr int GR = BK / 8;
    constexpr int AG = 64 * GR;
    constexpr int BG = BN * GR;
    const size_t actRow = (size_t)T * C;

    for (int k0 = 0; k0 < Kpad; k0 += BK) {
        #pragma unroll
        for (int gi = tid; gi < AG; gi += 256) {
            const int r = gi / GR, c8 = gi % GR;
            const int k = k0 + c8 * 8;
            const int b = b0 + r;
            uint4 v;
            if (k + 8 <= C) {
                v = *(const uint4*)(actb + (size_t)b * actRow + (size_t)t * C + k);
            } else if (k >= I) {
                v = make_uint4(0u, 0u, 0u, 0u);
            } else {
                v = *(const uint4*)(xg + (size_t)b * 5376 + (size_t)t * Gs + (k - C));
            }
            *(uint4*)&As[r][c8 * 8] = v;
        }
        #pragma unroll
        for (int gi = tid; gi < BG; gi += 256) {
            const int n = gi / GR, c8 = gi % GR;
            const int o = o0 + n;
            uint4 v = make_uint4(0u, 0u, 0u, 0u);
            if (o < O)
                v = *(const uint4*)(WbT + ((size_t)t * O + o) * Kpad + k0 + c8 * 8);
            *(uint4*)&Bs[n][c8 * 8] = v;
        }
        __syncthreads();
        #pragma unroll
        for (int ks = 0; ks < BK / 32; ks++) {
            const int koff = ks * 32 + quad * 8;
            short8 a0 = *(const short8*)&As[wm + l15][koff];
            short8 a1 = *(const short8*)&As[wm + 16 + l15][koff];
            #pragma unroll
            for (int fn = 0; fn < NF; fn++) {
                short8 bf = *(const short8*)&Bs[wn + fn * 16 + l15][koff];
                acc[0][fn] = __builtin_amdgcn_mfma_f32_16x16x32_bf16(a0, bf, acc[0][fn], 0, 0, 0);
                acc[1][fn] = __builtin_amdgcn_mfma_f32_16x16x32_bf16(a1, bf, acc[1][fn], 0, 0, 0);
            }
        }
        __syncthreads();
    }

    // epilogue + per-thread column partial sums (fp32, pre-rounding)
    float csum[NF], csum2[NF];
    #pragma unroll
    for (int fn = 0; fn < NF; fn++) { csum[fn] = 0.f; csum2[fn] = 0.f; }
    #pragma unroll
    for (int fm = 0; fm < 2; fm++)
        #pragma unroll
        for (int fn = 0; fn < NF; fn++)
            #pragma unroll
            for (int r = 0; r < 4; r++) {
                int m = wm + fm * 16 + quad * 4 + r;
                int o = o0 + wn + fn * 16 + l15;
                if (o < O) {
                    float v = acc[fm][fn][r] + bias[t * O + o];
                    h[(size_t)(b0 + m) * hstride + (size_t)t * O + o] = f2bf(v);
                    csum[fn] += v; csum2[fn] += v * v;
                }
            }
    #pragma unroll
    for (int fn = 0; fn < NF; fn++) {
        csum[fn]  += __shfl_xor(csum[fn], 16, 64);
        csum[fn]  += __shfl_xor(csum[fn], 32, 64);
        csum2[fn] += __shfl_xor(csum2[fn], 16, 64);
        csum2[fn] += __shfl_xor(csum2[fn], 32, 64);
    }
    if (quad == 0) {
        #pragma unroll
        for (int fn = 0; fn < NF; fn++) {
            ldsS[w & 1][wn + fn * 16 + l15]  = csum[fn];
            ldsS2[w & 1][wn + fn * 16 + l15] = csum2[fn];
        }
    }
    __syncthreads();
    if (tid < BN && o0 + tid < O) {
        int col = t * O + o0 + tid;
        size_t base = (size_t)blockIdx.y * 2 * TO;
        sp[base + col]      = ldsS[0][tid] + ldsS[1][tid];
        sp[base + TO + col] = ldsS2[0][tid] + ldsS2[1][tid];
    }
    __syncthreads();                       // all sp stores done (vmcnt drained)
    if (tid == 0) {
        __threadfence();                   // release sp
        lastFlag = (atomicAdd(&cnt[t], 1) == nPerT - 1);
    }
    __syncthreads();
    if (lastFlag) {
        __threadfence();                   // acquire others' sp
        for (int o = tid; o < O; o += 256) {
            int col = t * O + o;
            float fs = 0.f, fs2 = 0.f;
            for (int c2 = 0; c2 < 32; c2++) {
                fs  += sp[(size_t)c2 * 2 * TO + col];
                fs2 += sp[(size_t)c2 * 2 * TO + TO + col];
            }
            float mu = fs * (1.f / BDIM);
            float var = fs2 * (1.f / BDIM) - mu * mu;
            float scale = rsqrtf(var + 1e-5f) * g[col];
            ss[col] = scale;
            ss[TO + col] = bb[col] - mu * scale;
        }
    }
}

// ---- big-stage GEMM (s1/s0): 128-row tile, BK=32, dbuf LDS, XCD-swizzled 1D grid
template <int BN>
__global__ __launch_bounds__(256) void gemm_split(
    const unsigned short* __restrict__ A,     // [2048][aStride] bf16 (zero-padded)
    const unsigned short* __restrict__ WbT,   // [T][Npad][Kpad] bf16 (zero-padded)
    float* __restrict__ partial,              // [KS][2048][TNpad]
    int aStride, int tStride, int Kpad, int Npad, int KS, int TNpad,
    int nTiles, int TKS)
{
    const int tid = threadIdx.x;
    const int lane = tid & 63, w = tid >> 6;
    const int l15 = lane & 15, quad = lane >> 4;

    // swizzled decode: id = c + 8*(q*nTiles + n); group = q*8+c
    const int id = blockIdx.x;
    const int c = id & 7;
    const int tmp = id >> 3;
    const int n = tmp % nTiles;
    const int q = tmp / nTiles;
    const int group = q * 8 + c;
    const int b0 = (group / TKS) * 128;
    const int rem = group % TKS;
    const int t = rem / KS;
    const int ksIdx = rem - t * KS;
    const int n0 = n * BN;

    __shared__ __align__(16) unsigned short As[2][128 * 32];
    __shared__ __align__(16) unsigned short Bs[2][BN * 32];

    const int S = Kpad >> 5;
    const int qb = S / KS, rb = S % KS;
    const int beg = ksIdx * qb + (ksIdx < rb ? ksIdx : rb);
    const int cnt = qb + (ksIdx < rb ? 1 : 0);

    constexpr int NF = BN / 32;
    const int wm = (w & 1) * 64;
    const int wn = (w >> 1) * (BN / 2);

    float4v acc[4][NF];
    #pragma unroll
    for (int a = 0; a < 4; a++)
        #pragma unroll
        for (int b = 0; b < NF; b++)
            acc[a][b] = (float4v){0.f, 0.f, 0.f, 0.f};

    const unsigned short* aSrc[2];
    int aOff[2];
    #pragma unroll
    for (int j = 0; j < 2; j++) {
        int s = (w * 2 + j) * 64 + lane;
        int r = s >> 2, kg = (s & 3) ^ ((r >> 1) & 3);
        aSrc[j] = A + (size_t)(b0 + r) * aStride + (size_t)t * tStride + kg * 8;
        aOff[j] = (w * 2 + j) * 512;
    }
    constexpr int BCALLS = (BN == 128) ? 2 : 1;
    const unsigned short* bSrc[BCALLS];
    int bOff[BCALLS];
    #pragma unroll
    for (int j = 0; j < BCALLS; j++) {
        int s = (w * BCALLS + j) * 64 + lane;
        int r = s >> 2, kg = (s & 3) ^ ((r >> 1) & 3);
        bSrc[j] = WbT + ((size_t)t * Npad + n0 + r) * Kpad + kg * 8;
        bOff[j] = (w * BCALLS + j) * 512;
    }

    {
        const int k0 = beg << 5;
        #pragma unroll
        for (int j = 0; j < 2; j++)      stage16(aSrc[j] + k0, &As[0][aOff[j]], lane);
        #pragma unroll
        for (int j = 0; j < BCALLS; j++) stage16(bSrc[j] + k0, &Bs[0][bOff[j]], lane);
    }

    for (int s = 0; s < cnt; s++) {
        const int cur = s & 1;
        __syncthreads();
        if (s + 1 < cnt) {
            const int k1 = (beg + s + 1) << 5;
            #pragma unroll
            for (int j = 0; j < 2; j++)      stage16(aSrc[j] + k1, &As[cur ^ 1][aOff[j]], lane);
            #pragma unroll
            for (int j = 0; j < BCALLS; j++) stage16(bSrc[j] + k1, &Bs[cur ^ 1][bOff[j]], lane);
        }
        short8 af[4];
        #pragma unroll
        for (int fm = 0; fm < 4; fm++) {
            int m = wm + fm * 16 + l15;
            int pos = quad ^ ((m >> 1) & 3);
            af[fm] = *(const short8*)&As[cur][(m * 4 + pos) * 8];
        }
        short8 bfr[NF];
        #pragma unroll
        for (int fn = 0; fn < NF; fn++) {
            int nn = wn + fn * 16 + l15;
            int pos = quad ^ ((nn >> 1) & 3);
            bfr[fn] = *(const short8*)&Bs[cur][(nn * 4 + pos) * 8];
        }
        #pragma unroll
        for (int fm = 0; fm < 4; fm++)
            #pragma unroll
            for (int fn = 0; fn < NF; fn++)
                acc[fm][fn] = __builtin_amdgcn_mfma_f32_16x16x32_bf16(af[fm], bfr[fn], acc[fm][fn], 0, 0, 0);
    }

    const size_t pBase = ((size_t)ksIdx * BDIM + b0) * TNpad + (size_t)t * Npad + n0;
    #pragma unroll
    for (int fm = 0; fm < 4; fm++)
        #pragma unroll
        for (int r = 0; r < 4; r++) {
            const int m = wm + fm * 16 + quad * 4 + r;
            float* prow = partial + pBase + (size_t)m * TNpad + wn;
            #pragma unroll
            for (int fn = 0; fn < NF; fn++)
                prow[fn * 16 + l15] = acc[fm][fn][r];
        }
}

// ---- split-K reduce + bias + h + stats + last-block fold (body) ----
static __device__ __forceinline__ void reduce_body(
    const float* __restrict__ partial, const float* __restrict__ bias,
    unsigned short* __restrict__ h, float* __restrict__ sp,
    int* __restrict__ cnt, const float* __restrict__ g,
    const float* __restrict__ bb, float* __restrict__ ss,
    int T, int O, int Npad, int KS, int hstride, int TO, int x, int chunk, int tid)
{
    __shared__ float redS[4][64], redS2[4][64];
    __shared__ int lastFlag;
    const int colL = tid & 63;
    const int cr = tid >> 6;
    const int col = x * 64 + colL;
    float s = 0.f, s2 = 0.f;
    if (col < TO) {
        int t = col / O, o = col - t * O;
        const size_t TNpad = (size_t)T * Npad;
        const size_t pcol = (size_t)t * Npad + o;
        const float bv = bias[col];
        const int row0 = chunk * 128 + cr * 32;
        for (int r = 0; r < 32; r++) {
            const int row = row0 + r;
            const float* p = partial + (size_t)row * TNpad + pcol;
            float v = bv;
            for (int ks = 0; ks < KS; ks++) v += p[(size_t)ks * BDIM * TNpad];
            h[(size_t)row * hstride + col] = f2bf(v);
            s += v; s2 += v * v;
        }
    }
    redS[cr][colL] = s; redS2[cr][colL] = s2;
    __syncthreads();
    if (cr == 0 && col < TO) {
        float ts  = redS[0][colL] + redS[1][colL] + redS[2][colL] + redS[3][colL];
        float ts2 = redS2[0][colL] + redS2[1][colL] + redS2[2][colL] + redS2[3][colL];
        sp[(size_t)chunk * 2 * TO + col] = ts;
        sp[(size_t)chunk * 2 * TO + TO + col] = ts2;
    }
    __syncthreads();                     // sp stores drained
    if (tid == 0) {
        __threadfence();
        lastFlag = (atomicAdd(&cnt[x], 1) == 15);
    }
    __syncthreads();
    if (lastFlag && tid < 64) {
        __threadfence();
        int col2 = x * 64 + tid;
        if (col2 < TO) {
            float fs = 0.f, fs2 = 0.f;
            for (int ch = 0; ch < 16; ch++) {
                fs  += sp[(size_t)ch * 2 * TO + col2];
                fs2 += sp[(size_t)ch * 2 * TO + TO + col2];
            }
            float mu = fs * (1.f / BDIM);
            float var = fs2 * (1.f / BDIM) - mu * mu;
            float scale = rsqrtf(var + 1e-5f) * g[col2];
            ss[col2] = scale;
            ss[TO + col2] = bb[col2] - mu * scale;
        }
    }
}

// s0: reduce only (grid 320 = 20 x-groups * 16 chunks)
__global__ __launch_bounds__(256) void reduce_fold(
    const float* __restrict__ partial, const float* __restrict__ bias,
    unsigned short* __restrict__ h, float* __restrict__ sp,
    int* __restrict__ cnt, const float* __restrict__ g,
    const float* __restrict__ bb, float* __restrict__ ss,
    int T, int O, int Npad, int KS, int hstride, int TO)
{
    reduce_body(partial, bias, h, sp, cnt, g, bb, ss, T, O, Npad, KS, hstride, TO,
                blockIdx.x % 20, blockIdx.x / 20, threadIdx.x);
}

// s1: reduce ∪ cvt_w0 (grid 320 + 6720 = 7040)
__global__ __launch_bounds__(256) void reduce_fold_cvt(
    const float* __restrict__ partial, const float* __restrict__ bias,
    unsigned short* __restrict__ h, float* __restrict__ sp,
    int* __restrict__ cnt, const float* __restrict__ g,
    const float* __restrict__ bb, float* __restrict__ ss,
    int T, int O, int Npad, int KS, int hstride, int TO,
    const float* __restrict__ W0, unsigned short* __restrict__ wbt0)
{
    const int bid = blockIdx.x;
    if (bid < 320) {
        reduce_body(partial, bias, h, sp, cnt, g, bb, ss, T, O, Npad, KS, hstride, TO,
                    bid % 20, bid / 20, threadIdx.x);
    } else {
        int l = bid - 320;                 // cvt_w0: I=5328 O=1229 Npad=1280 Kpad=5376
        int bx = l % 168, by = l / 168;
        cvt_w_body(W0, wbt0, 5328, 1229, 1280, 5376, bx * 32, by * 32, threadIdx.x);
    }
}

// ---- vectorized BN+tanh+head for O=20 in-place stages (s4/s3) ----
template <int GPT>
__global__ __launch_bounds__(256) void bn_tanh_head_vec(
    unsigned short* hact, const float* __restrict__ ss,
    const float* __restrict__ hw, const float* __restrict__ hb,
    float* __restrict__ out,
    int T, int rowGran, int RPB, int hstride, int head_off)
{
    __shared__ float headAcc[256];
    const int tid = threadIdx.x;
    headAcc[tid] = 0.f;
    __syncthreads();
    const int b0 = blockIdx.x * RPB;

    uint2 hv[GPT];
    #pragma unroll
    for (int j = 0; j < GPT; j++) {
        int G = tid + j * 256;
        int r = G / rowGran, gg = G % rowGran;
        hv[j] = *(const uint2*)(hact + (size_t)(b0 + r) * hstride + gg * 4);
    }
    #pragma unroll
    for (int j = 0; j < GPT; j++) {
        int G = tid + j * 256;
        int r = G / rowGran, gg = G % rowGran;
        int c = gg * 4;
        float4 sc = *(const float4*)(ss + c);
        float4 sh = *(const float4*)(ss + hstride + c);
        float4 w4 = *(const float4*)(hw + c);
        union { unsigned short u[4]; uint2 v; } iv, ov;
        iv.v = hv[j];
        float a0 = fast_tanh(bf2f(iv.u[0]) * sc.x + sh.x);
        float a1 = fast_tanh(bf2f(iv.u[1]) * sc.y + sh.y);
        float a2 = fast_tanh(bf2f(iv.u[2]) * sc.z + sh.z);
        float a3 = fast_tanh(bf2f(iv.u[3]) * sc.w + sh.w);
        ov.u[0] = f2bf(a0); ov.u[1] = f2bf(a1); ov.u[2] = f2bf(a2); ov.u[3] = f2bf(a3);
        *(uint2*)(hact + (size_t)(b0 + r) * hstride + c) = ov.v;
        float partial = a0 * w4.x + a1 * w4.y + a2 * w4.z + a3 * w4.w;
        int t = gg / 5;
        atomicAdd(&headAcc[r * T + t], partial);
    }
    __syncthreads();
    if (tid < RPB * T) {
        int r = tid / T, t = tid % T;
        out[(size_t)(b0 + r) * OUTW + head_off + t] = headAcc[tid] + hb[t];
    }
}

// ---- BN + tanh + strided act store + head — WAVE variant ----
__global__ __launch_bounds__(256) void bn_tanh_head(
    const unsigned short* __restrict__ h, const float* __restrict__ ss,
    const float* __restrict__ hw, const float* __restrict__ hb,
    unsigned short* __restrict__ actOut, float* __restrict__ out,
    int T, int O, int hstride, int aRow, int GT, int GS, int head_off, int TO)
{
    int wid  = (blockIdx.x * 256 + threadIdx.x) >> 6;
    int lane = threadIdx.x & 63;
    int b = wid / T;
    int t = wid % T;
    const size_t hbase = (size_t)b * hstride + (size_t)t * O;
    const size_t abase = (size_t)b * aRow + (size_t)(t / GT) * GS + (size_t)(t % GT) * O;
    float hsum = 0.f;
    for (int o = lane; o < O; o += 64) {
        int col = t * O + o;
        float a = fast_tanh(bf2f(h[hbase + o]) * ss[col] + ss[TO + col]);
        if (actOut) actOut[abase + o] = f2bf(a);
        hsum += a * hw[col];
    }
    #pragma unroll
    for (int off = 32; off > 0; off >>= 1) hsum += __shfl_down(hsum, off, 64);
    if (lane == 0) out[(size_t)b * OUTW + head_off + t] = hsum + hb[t];
}

extern "C" void kernel_launch(void* const* d_in, const int* in_sizes, int n_in,
                              void* d_out, int out_size, void* d_ws, size_t ws_size,
                              hipStream_t stream)
{
    const float* x = (const float*)d_in[0];
    float* out = (float*)d_out;
    char* ws = (char*)d_ws;

    // ws layout (bytes)
    unsigned short* wbt  = (unsigned short*)(ws);              // 13,762,560
    unsigned short* ain0 = (unsigned short*)(ws + 13762560);   // 22,020,096 (2048x5376)
    unsigned short* bufA = (unsigned short*)(ws + 35782656);   // 20,971,520
    unsigned short* bufB = (unsigned short*)(ws + 56754176);   //  5,242,880
    unsigned short* ain1 = (unsigned short*)(ws + 61997056);   // 22,020,096
    unsigned short* bufC = (unsigned short*)(ws + 84017152);   //  5,046,272
    float*          ss   = (float*)(ws + 89063424);            //     40,960
    float*          sp0  = (float*)(ws + 89104384);            //    157,312 (16x2x1229)
    int*            cntB = (int*)(ws + 89261696);              //      1,504 (376 ints)
    // overlays (all dead at use time):
    float* partial = (float*)(ws + 35782656);   // s1: 21 MB (=bufA), s0: 41.9 MB
    float* sp4 = (float*)bufC;
    float* sp3 = (float*)bufC;
    float* sp2 = (float*)bufA;
    float* sp1 = (float*)bufB;
    unsigned short* xg = ain0 + 1232;           // full bf16 x copy, row stride 5376
    int* cntS4 = cntB;        // 256
    int* cntS3 = cntB + 256;  // 64
    int* cntS2 = cntB + 320;  // 16
    int* cnt1  = cntB + 336;  // 20
    int* cnt0  = cntB + 356;  // 20

    const float* W4 = (const float*)d_in[1];  const float* b4 = (const float*)d_in[2];
    const float* g4 = (const float*)d_in[3];  const float* bb4 = (const float*)d_in[4];
    const float* hw4 = (const float*)d_in[5]; const float* hb4 = (const float*)d_in[6];
    const float* W3 = (const float*)d_in[7];  const float* b3 = (const float*)d_in[8];
    const float* g3 = (const float*)d_in[9];  const float* bb3 = (const float*)d_in[10];
    const float* hw3 = (const float*)d_in[11]; const float* hb3 = (const float*)d_in[12];
    const float* W2 = (const float*)d_in[13]; const float* b2 = (const float*)d_in[14];
    const float* g2 = (const float*)d_in[15]; const float* bb2 = (const float*)d_in[16];
    const float* hw2 = (const float*)d_in[17]; const float* hb2 = (const float*)d_in[18];
    const float* W1 = (const float*)d_in[19]; const float* b1 = (const float*)d_in[20];
    const float* g1 = (const float*)d_in[21]; const float* bb1 = (const float*)d_in[22];
    const float* hw1 = (const float*)d_in[23]; const float* hb1 = (const float*)d_in[24];
    const float* W0 = (const float*)d_in[25]; const float* b0_ = (const float*)d_in[26];
    const float* g0 = (const float*)d_in[27]; const float* bb0 = (const float*)d_in[28];
    const float* hw0 = (const float*)d_in[29]; const float* hb0 = (const float*)d_in[30];

    // 1: pack + W4..W1 conversions + counter zero
    prep<<<7185, 256, 0, stream>>>(x, ain0, ain1, W4, W3, W2, W1, wbt, cntB);

    // 2-3: s4 (T=256 I=16 O=20 Kpad=32, WbT @0)
    gemm_small<32, 32><<<dim3(1, 32, 256), 256, 0, stream>>>(
        nullptr, xg, wbt, b4, bufA, sp4, cntS4, g4, bb4, ss,
        256, 16, 20, 0, 16, 32, 5120, 5120, 32);
    bn_tanh_head_vec<5><<<BDIM, 256, 0, stream>>>(bufA, ss, hw4, hb4, out, 256, 1280, 1, 5120, 0);

    // 4-5: s3 (T=64 I=144 O=20 Kpad=192, WbT @163840)
    gemm_small<32, 64><<<dim3(1, 32, 64), 256, 0, stream>>>(
        bufA, xg, wbt + 163840, b3, bufB, sp3, cntS3, g3, bb3, ss,
        64, 144, 20, 80, 64, 192, 1280, 1280, 32);
    bn_tanh_head_vec<5><<<BDIM / 4, 256, 0, stream>>>(bufB, ss, hw3, hb3, out, 64, 320, 4, 1280, 256);

    // 6-7: s2 (T=16 I=336 O=77 Kpad=384, WbT @409600)
    gemm_small<64, 64><<<dim3(2, 32, 16), 256, 0, stream>>>(
        bufB, xg, wbt + 409600, b2, bufC, sp2, cntS2, g2, bb2, ss,
        16, 336, 77, 80, 256, 384, 1232, 1232, 64);
    bn_tanh_head<<<BDIM * 16 / 4, 256, 0, stream>>>(bufC, ss, hw2, hb2,
                                                    ain1, out, 16, 77, 1232, 5376, 4, 1344, 320, 1232);

    // 8-10: s1 (T=4 I=1332 O=308 Kpad=1344 Npad=320 KS=2, WbT @882688)
    gemm_split<64><<<640, 256, 0, stream>>>(ain1, wbt + 882688, partial,
                                            5376, 1344, 1344, 320, 2, 1280, 5, 8);
    reduce_fold_cvt<<<7040, 256, 0, stream>>>(partial, b1, bufC, sp1, cnt1, g1, bb1, ss,
                                              4, 308, 320, 2, 1232, 1232, W0, wbt);
    bn_tanh_head<<<BDIM * 4 / 4, 256, 0, stream>>>(bufC, ss, hw1, hb1,
                                                   ain0, out, 4, 308, 1232, 5376, 4, 0, 336, 1232);

    // 11-13: s0 (T=1 I=5328 O=1229 Kpad=5376 Npad=1280 KS=4)
    gemm_split<128><<<640, 256, 0, stream>>>(ain0, wbt, partial,
                                             5376, 0, 5376, 1280, 4, 1280, 10, 4);
    reduce_fold<<<320, 256, 0, stream>>>(partial, b0_, bufC, sp0, cnt0, g0, bb0, ss,
                                         1, 1229, 1280, 4, 1232, 1229);
    bn_tanh_head<<<BDIM / 4, 256, 0, stream>>>(bufC, ss, hw0, hb0,
                                               nullptr, out, 1, 1229, 1232, 1232, 1, 0, 340, 1229);
}

// Round 12
// 452.775 us; speedup vs baseline: 2.1604x; 2.1604x over previous
//
#include <hip/hip_runtime.h>
#include <hip/hip_bf16.h>

// DCell forward, bf16-MFMA. Round-12: revert round-10's fence-based fold
// (per-block __threadfence = device-scope drain per block = 2x regression),
// keep fence-free unions, double s0 gemm occupancy via BN=64/KS=4.
//  1 prep          : pack_x ∪ cvt_w_all (W4..W1)
//  2-4   s4: gemm_small(+fused col stats) -> bn_scaleN -> bn_tanh_head_vec
//  5-7   s3: same
//  8-10  s2: gemm_small -> bn_scaleN -> bn_tanh_head (wave, -> ain1)
//  11 gemm_split<64> s1 (BK=32 dbuf, XCD-swizzled 1D grid, KS=2)
//  12 reduce_stats_cvt s1 (split-K reduce+bias+h+stats ∪ cvt_w0)
//  13 bn_scaleN s1   14 bn_tanh_head s1 (-> ain0)
//  15 gemm_split<64> s0 (KS=4, 1280 blocks = 5/CU; was BN=128/640 blocks)
//  16 reduce_stats s0  17 bn_scaleN s0  18 bn_tanh_head s0 (no act store)
// Stage cfg (T,I,O,C,Gs): s4(256,16,20,0,16) s3(64,144,20,80,64)
//  s2(16,336,77,80,256) s1(4,1332,308,308,1024) s0(1,5328,1229,1232,4096)

#define BDIM 2048
#define OUTW 341

typedef __attribute__((ext_vector_type(8))) short short8;
typedef __attribute__((ext_vector_type(4))) float float4v;

static __device__ __forceinline__ unsigned short f2bf(float f) {
    union { float f; unsigned u; } c{f};
    unsigned r = c.u + 0x7FFF + ((c.u >> 16) & 1);  // RNE
    return (unsigned short)(r >> 16);
}
static __device__ __forceinline__ float bf2f(unsigned short s) {
    union { unsigned u; float f; } c{(unsigned)s << 16};
    return c.f;
}

static __device__ __forceinline__ float fast_tanh(float x) {
    float ax = __builtin_fabsf(x);
    float e  = __builtin_amdgcn_exp2f(ax * 2.8853900817779268f);  // e^{2|x|}
    float r  = 1.f - 2.f * __builtin_amdgcn_rcpf(e + 1.f);
    return __builtin_copysignf(r, x);
}

// async global->LDS, 16B/lane: wave-uniform base + lane*16.
static __device__ __forceinline__ void stage16(const void* g, void* ldsBase, int lane) {
#if __has_builtin(__builtin_amdgcn_global_load_lds)
    __builtin_amdgcn_global_load_lds(
        (const __attribute__((address_space(1))) unsigned int*)(uintptr_t)g,
        (__attribute__((address_space(3))) unsigned int*)(unsigned int)(uintptr_t)ldsBase,
        16, 0, 0);
#else
    *(uint4*)((char*)ldsBase + lane * 16) = *(const uint4*)g;
#endif
}

// ---- W[t][I][O] fp32 -> WbT[t][Npad][Kpad] bf16 transpose core ----
static __device__ __forceinline__ void cvt_w_body(const float* Wt, unsigned short* dst,
                                                  int I, int O, int Npad, int Kpad,
                                                  int i0, int o0, int tid) {
    __shared__ unsigned short tile[32][33];
    const int c = tid & 31, r0 = tid >> 5;
    #pragma unroll
    for (int rr = 0; rr < 4; rr++) {
        int i = i0 + r0 + rr * 8, o = o0 + c;
        float v = (i < I && o < O) ? Wt[(size_t)i * O + o] : 0.f;
        tile[r0 + rr * 8][c] = f2bf(v);
    }
    __syncthreads();
    #pragma unroll
    for (int rr = 0; rr < 4; rr++) {
        int o = o0 + r0 + rr * 8, k = i0 + c;
        if (o < Npad) dst[(size_t)o * Kpad + k] = tile[c][r0 + rr * 8];
    }
}

// ---- prep: pack_x ∪ cvt_w_all(W4..W1) — no fences, no counters ----
__global__ __launch_bounds__(256) void prep(const float* __restrict__ x,
                                            unsigned short* __restrict__ ain0,
                                            unsigned short* __restrict__ ain1,
                                            const float* __restrict__ W4,
                                            const float* __restrict__ W3,
                                            const float* __restrict__ W2,
                                            const float* __restrict__ W1,
                                            unsigned short* __restrict__ wbt) {
    const int bid = blockIdx.x;
    if (bid < 4288) {                         // pack_x region
        const int MAIN = BDIM * 512;          // 8-float units
        int i = bid * 256 + threadIdx.x;
        if (i < MAIN) {
            int b = i >> 9, j = i & 511;
            const float* xp = x + (size_t)b * 4096 + j * 8;
            float4 lo = *(const float4*)xp, hi = *(const float4*)(xp + 4);
            union { unsigned short u[8]; uint4 v4; uint2 v2[2]; } t;
            t.u[0] = f2bf(lo.x); t.u[1] = f2bf(lo.y); t.u[2] = f2bf(lo.z); t.u[3] = f2bf(lo.w);
            t.u[4] = f2bf(hi.x); t.u[5] = f2bf(hi.y); t.u[6] = f2bf(hi.z); t.u[7] = f2bf(hi.w);
            *(uint4*)(ain0 + (size_t)b * 5376 + 1232 + j * 8) = t.v4;
            int gi = j * 8, tt = gi >> 10, u = gi & 1023;
            unsigned short* d1 = ain1 + (size_t)b * 5376 + tt * 1344 + 308 + u;
            *(uint2*)d1 = t.v2[0];
            *(uint2*)(d1 + 4) = t.v2[1];
            return;
        }
        int zi = i - MAIN;
        const int ZU = BDIM * 12;
        if (zi < ZU) {
            int b = zi / 12, u = zi % 12;
            *(uint2*)(ain0 + (size_t)b * 5376 + 5328 + u * 4) = make_uint2(0u, 0u);
        } else if (zi < 2 * ZU) {
            zi -= ZU;
            int b = zi / 12, u = zi % 12, tt = u / 3, k = u % 3;
            *(uint2*)(ain1 + (size_t)b * 5376 + tt * 1344 + 1332 + k * 4) = make_uint2(0u, 0u);
        }
        return;
    }
    int b2 = bid - 4288;                      // cvt_w_all region
    const float* W; unsigned short* dst;
    int I, O, Npad, Kpad, gx, gy, local;
    if (b2 < 256)       { W = W4; dst = wbt;           I = 16;   O = 20;  Npad = 20;  Kpad = 32;   gx = 1;  gy = 1;  local = b2; }
    else if (b2 < 640)  { W = W3; dst = wbt + 163840;  I = 144;  O = 20;  Npad = 20;  Kpad = 192;  gx = 6;  gy = 1;  local = b2 - 256; }
    else if (b2 < 1216) { W = W2; dst = wbt + 409600;  I = 336;  O = 77;  Npad = 77;  Kpad = 384;  gx = 12; gy = 3;  local = b2 - 640; }
    else                { W = W1; dst = wbt + 882688;  I = 1332; O = 308; Npad = 320; Kpad = 1344; gx = 42; gy = 10; local = b2 - 1216; }
    int per = gx * gy;
    int t = local / per, rem = local % per;
    int by = rem / gx, bx = rem % gx;
    cvt_w_body(W + (size_t)t * I * O, dst + (size_t)t * Npad * Kpad,
               I, O, Npad, Kpad, bx * 32, by * 32, threadIdx.x);
}

// ---- small-stage GEMM + fused column stats (chunk = blockIdx.y, 32 chunks of 64 rows)
template <int BN, int BK>
__global__ __launch_bounds__(256) void gemm_small(
    const unsigned short* __restrict__ actb,  // [B][T*C] bf16 (null if C==0)
    const unsigned short* __restrict__ xg,    // bf16 x copy, row stride 5376
    const unsigned short* __restrict__ WbT,   // [T][O][Kpad] bf16
    const float* __restrict__ bias,
    unsigned short* __restrict__ h,           // [B][hstride]
    float* __restrict__ sp,                   // [32][2*TO] col-sum partials
    int T, int I, int O, int C, int Gs, int Kpad, int hstride, int TO)
{
    const int t  = blockIdx.z;
    const int b0 = blockIdx.y * 64;
    const int o0 = blockIdx.x * BN;
    const int tid = threadIdx.x;
    const int lane = tid & 63;
    const int w = tid >> 6;
    const int l15 = lane & 15;
    const int quad = lane >> 4;

    constexpr int NF = BN / 32;
    const int wm = (w & 1) * 32;
    const int wn = (w >> 1) * (BN / 2);

    __shared__ __align__(16) unsigned short As[64][BK + 8];
    __shared__ __align__(16) unsigned short Bs[BN][BK + 8];
    __shared__ float ldsS[2][BN], ldsS2[2][BN];

    float4v acc[2][NF];
    #pragma unroll
    for (int a = 0; a < 2; a++)
        #pragma unroll
        for (int b = 0; b < NF; b++)
            acc[a][b] = (float4v){0.f, 0.f, 0.f, 0.f};

    constexpr int GR = BK / 8;
    constexpr int AG = 64 * GR;
    constexpr int BG = BN * GR;
    const size_t actRow = (size_t)T * C;

    for (int k0 = 0; k0 < Kpad; k0 += BK) {
        #pragma unroll
        for (int gi = tid; gi < AG; gi += 256) {
            const int r = gi / GR, c8 = gi % GR;
            const int k = k0 + c8 * 8;
            const int b = b0 + r;
            uint4 v;
            if (k + 8 <= C) {
                v = *(const uint4*)(actb + (size_t)b * actRow + (size_t)t * C + k);
            } else if (k >= I) {
                v = make_uint4(0u, 0u, 0u, 0u);
            } else {
                v = *(const uint4*)(xg + (size_t)b * 5376 + (size_t)t * Gs + (k - C));
            }
            *(uint4*)&As[r][c8 * 8] = v;
        }
        #pragma unroll
        for (int gi = tid; gi < BG; gi += 256) {
            const int n = gi / GR, c8 = gi % GR;
            const int o = o0 + n;
            uint4 v = make_uint4(0u, 0u, 0u, 0u);
            if (o < O)
                v = *(const uint4*)(WbT + ((size_t)t * O + o) * Kpad + k0 + c8 * 8);
            *(uint4*)&Bs[n][c8 * 8] = v;
        }
        __syncthreads();
        #pragma unroll
        for (int ks = 0; ks < BK / 32; ks++) {
            const int koff = ks * 32 + quad * 8;
            short8 a0 = *(const short8*)&As[wm + l15][koff];
            short8 a1 = *(const short8*)&As[wm + 16 + l15][koff];
            #pragma unroll
            for (int fn = 0; fn < NF; fn++) {
                short8 bf = *(const short8*)&Bs[wn + fn * 16 + l15][koff];
                acc[0][fn] = __builtin_amdgcn_mfma_f32_16x16x32_bf16(a0, bf, acc[0][fn], 0, 0, 0);
                acc[1][fn] = __builtin_amdgcn_mfma_f32_16x16x32_bf16(a1, bf, acc[1][fn], 0, 0, 0);
            }
        }
        __syncthreads();
    }

    // epilogue + per-thread column partial sums (fp32, pre-rounding)
    float csum[NF], csum2[NF];
    #pragma unroll
    for (int fn = 0; fn < NF; fn++) { csum[fn] = 0.f; csum2[fn] = 0.f; }
    #pragma unroll
    for (int fm = 0; fm < 2; fm++)
        #pragma unroll
        for (int fn = 0; fn < NF; fn++)
            #pragma unroll
            for (int r = 0; r < 4; r++) {
                int m = wm + fm * 16 + quad * 4 + r;
                int o = o0 + wn + fn * 16 + l15;
                if (o < O) {
                    float v = acc[fm][fn][r] + bias[t * O + o];
                    h[(size_t)(b0 + m) * hstride + (size_t)t * O + o] = f2bf(v);
                    csum[fn] += v; csum2[fn] += v * v;
                }
            }
    #pragma unroll
    for (int fn = 0; fn < NF; fn++) {
        csum[fn]  += __shfl_xor(csum[fn], 16, 64);
        csum[fn]  += __shfl_xor(csum[fn], 32, 64);
        csum2[fn] += __shfl_xor(csum2[fn], 16, 64);
        csum2[fn] += __shfl_xor(csum2[fn], 32, 64);
    }
    if (quad == 0) {
        #pragma unroll
        for (int fn = 0; fn < NF; fn++) {
            ldsS[w & 1][wn + fn * 16 + l15]  = csum[fn];
            ldsS2[w & 1][wn + fn * 16 + l15] = csum2[fn];
        }
    }
    __syncthreads();
    if (tid < BN && o0 + tid < O) {
        int col = t * O + o0 + tid;
        size_t base = (size_t)blockIdx.y * 2 * TO;
        sp[base + col]      = ldsS[0][tid] + ldsS[1][tid];
        sp[base + TO + col] = ldsS2[0][tid] + ldsS2[1][tid];
    }
}

// ---- big-stage GEMM (s1/s0): 128-row tile, BK=32, dbuf LDS, XCD-swizzled 1D grid
template <int BN>
__global__ __launch_bounds__(256) void gemm_split(
    const unsigned short* __restrict__ A,     // [2048][aStride] bf16 (zero-padded)
    const unsigned short* __restrict__ WbT,   // [T][Npad][Kpad] bf16 (zero-padded)
    float* __restrict__ partial,              // [KS][2048][TNpad]
    int aStride, int tStride, int Kpad, int Npad, int KS, int TNpad,
    int nTiles, int TKS)
{
    const int tid = threadIdx.x;
    const int lane = tid & 63, w = tid >> 6;
    const int l15 = lane & 15, quad = lane >> 4;

    // swizzled decode: id = c + 8*(q*nTiles + n); group = q*8+c
    const int id = blockIdx.x;
    const int c = id & 7;
    const int tmp = id >> 3;
    const int n = tmp % nTiles;
    const int q = tmp / nTiles;
    const int group = q * 8 + c;
    const int b0 = (group / TKS) * 128;
    const int rem = group % TKS;
    const int t = rem / KS;
    const int ksIdx = rem - t * KS;
    const int n0 = n * BN;

    __shared__ __align__(16) unsigned short As[2][128 * 32];
    __shared__ __align__(16) unsigned short Bs[2][BN * 32];

    const int S = Kpad >> 5;
    const int qb = S / KS, rb = S % KS;
    const int beg = ksIdx * qb + (ksIdx < rb ? ksIdx : rb);
    const int cnt = qb + (ksIdx < rb ? 1 : 0);

    constexpr int NF = BN / 32;
    const int wm = (w & 1) * 64;
    const int wn = (w >> 1) * (BN / 2);

    float4v acc[4][NF];
    #pragma unroll
    for (int a = 0; a < 4; a++)
        #pragma unroll
        for (int b = 0; b < NF; b++)
            acc[a][b] = (float4v){0.f, 0.f, 0.f, 0.f};

    const unsigned short* aSrc[2];
    int aOff[2];
    #pragma unroll
    for (int j = 0; j < 2; j++) {
        int s = (w * 2 + j) * 64 + lane;
        int r = s >> 2, kg = (s & 3) ^ ((r >> 1) & 3);
        aSrc[j] = A + (size_t)(b0 + r) * aStride + (size_t)t * tStride + kg * 8;
        aOff[j] = (w * 2 + j) * 512;
    }
    constexpr int BCALLS = (BN == 128) ? 2 : 1;
    const unsigned short* bSrc[BCALLS];
    int bOff[BCALLS];
    #pragma unroll
    for (int j = 0; j < BCALLS; j++) {
        int s = (w * BCALLS + j) * 64 + lane;
        int r = s >> 2, kg = (s & 3) ^ ((r >> 1) & 3);
        bSrc[j] = WbT + ((size_t)t * Npad + n0 + r) * Kpad + kg * 8;
        bOff[j] = (w * BCALLS + j) * 512;
    }

    {
        const int k0 = beg << 5;
        #pragma unroll
        for (int j = 0; j < 2; j++)      stage16(aSrc[j] + k0, &As[0][aOff[j]], lane);
        #pragma unroll
        for (int j = 0; j < BCALLS; j++) stage16(bSrc[j] + k0, &Bs[0][bOff[j]], lane);
    }

    for (int s = 0; s < cnt; s++) {
        const int cur = s & 1;
        __syncthreads();   // drains cur-buf loads (in flight since prev iter) + prev compute
        if (s + 1 < cnt) {
            const int k1 = (beg + s + 1) << 5;
            #pragma unroll
            for (int j = 0; j < 2; j++)      stage16(aSrc[j] + k1, &As[cur ^ 1][aOff[j]], lane);
            #pragma unroll
            for (int j = 0; j < BCALLS; j++) stage16(bSrc[j] + k1, &Bs[cur ^ 1][bOff[j]], lane);
        }
        short8 af[4];
        #pragma unroll
        for (int fm = 0; fm < 4; fm++) {
            int m = wm + fm * 16 + l15;
            int pos = quad ^ ((m >> 1) & 3);
            af[fm] = *(const short8*)&As[cur][(m * 4 + pos) * 8];
        }
        short8 bfr[NF];
        #pragma unroll
        for (int fn = 0; fn < NF; fn++) {
            int nn = wn + fn * 16 + l15;
            int pos = quad ^ ((nn >> 1) & 3);
            bfr[fn] = *(const short8*)&Bs[cur][(nn * 4 + pos) * 8];
        }
        #pragma unroll
        for (int fm = 0; fm < 4; fm++)
            #pragma unroll
            for (int fn = 0; fn < NF; fn++)
                acc[fm][fn] = __builtin_amdgcn_mfma_f32_16x16x32_bf16(af[fm], bfr[fn], acc[fm][fn], 0, 0, 0);
    }

    const size_t pBase = ((size_t)ksIdx * BDIM + b0) * TNpad + (size_t)t * Npad + n0;
    #pragma unroll
    for (int fm = 0; fm < 4; fm++)
        #pragma unroll
        for (int r = 0; r < 4; r++) {
            const int m = wm + fm * 16 + quad * 4 + r;
            float* prow = partial + pBase + (size_t)m * TNpad + wn;
            #pragma unroll
            for (int fn = 0; fn < NF; fn++)
                prow[fn * 16 + l15] = acc[fm][fn][r];
        }
}

// ---- split-K reduce + bias + bf16 h store + per-chunk stats partials (body) ----
static __device__ __forceinline__ void reduce_body(
    const float* __restrict__ partial, const float* __restrict__ bias,
    unsigned short* __restrict__ h, float* __restrict__ sp,
    int T, int O, int Npad, int KS, int hstride, int TO, int x, int chunk, int tid)
{
    __shared__ float redS[4][64], redS2[4][64];
    const int colL = tid & 63;
    const int cr = tid >> 6;
    const int col = x * 64 + colL;
    float s = 0.f, s2 = 0.f;
    if (col < TO) {
        int t = col / O, o = col - t * O;
        const size_t TNpad = (size_t)T * Npad;
        const size_t pcol = (size_t)t * Npad + o;
        const float bv = bias[col];
        const int row0 = chunk * 128 + cr * 32;
        for (int r = 0; r < 32; r++) {
            const int row = row0 + r;
            const float* p = partial + (size_t)row * TNpad + pcol;
            float v = bv;
            for (int ks = 0; ks < KS; ks++) v += p[(size_t)ks * BDIM * TNpad];
            h[(size_t)row * hstride + col] = f2bf(v);
            s += v; s2 += v * v;
        }
    }
    redS[cr][colL] = s; redS2[cr][colL] = s2;
    __syncthreads();
    if (cr == 0 && col < TO) {
        float ts  = redS[0][colL] + redS[1][colL] + redS[2][colL] + redS[3][colL];
        float ts2 = redS2[0][colL] + redS2[1][colL] + redS2[2][colL] + redS2[3][colL];
        sp[(size_t)chunk * 2 * TO + col] = ts;
        sp[(size_t)chunk * 2 * TO + TO + col] = ts2;
    }
}

// s0: reduce only (grid 320 = 20 x-groups * 16 chunks)
__global__ __launch_bounds__(256) void reduce_stats(
    const float* __restrict__ partial, const float* __restrict__ bias,
    unsigned short* __restrict__ h, float* __restrict__ sp,
    int T, int O, int Npad, int KS, int hstride, int TO)
{
    reduce_body(partial, bias, h, sp, T, O, Npad, KS, hstride, TO,
                blockIdx.x % 20, blockIdx.x / 20, threadIdx.x);
}

// s1: reduce ∪ cvt_w0 (grid 320 + 6720 = 7040)
__global__ __launch_bounds__(256) void reduce_stats_cvt(
    const float* __restrict__ partial, const float* __restrict__ bias,
    unsigned short* __restrict__ h, float* __restrict__ sp,
    int T, int O, int Npad, int KS, int hstride, int TO,
    const float* __restrict__ W0, unsigned short* __restrict__ wbt0)
{
    const int bid = blockIdx.x;
    if (bid < 320) {
        reduce_body(partial, bias, h, sp, T, O, Npad, KS, hstride, TO,
                    bid % 20, bid / 20, threadIdx.x);
    } else {
        int l = bid - 320;                 // cvt_w0: I=5328 O=1229 Npad=1280 Kpad=5376
        int bx = l % 168, by = l / 168;
        cvt_w_body(W0, wbt0, 5328, 1229, 1280, 5376, bx * 32, by * 32, threadIdx.x);
    }
}

// ---- fold NC chunk partials -> per-col scale/shift ----
__global__ __launch_bounds__(256) void bn_scaleN(const float* __restrict__ sp,
                                                 const float* __restrict__ g,
                                                 const float* __restrict__ bb,
                                                 float* __restrict__ ss, int TO, int NC) {
    int col = blockIdx.x * 256 + threadIdx.x;
    if (col >= TO) return;
    float s = 0.f, s2 = 0.f;
    for (int c = 0; c < NC; c++) {
        s  += sp[(size_t)c * 2 * TO + col];
        s2 += sp[(size_t)c * 2 * TO + TO + col];
    }
    float mu = s * (1.f / BDIM);
    float var = s2 * (1.f / BDIM) - mu * mu;  // biased, matches jnp.var
    float scale = rsqrtf(var + 1e-5f) * g[col];
    ss[col] = scale;
    ss[TO + col] = bb[col] - mu * scale;
}

// ---- vectorized BN+tanh+head for O=20 in-place stages (s4/s3) ----
template <int GPT>
__global__ __launch_bounds__(256) void bn_tanh_head_vec(
    unsigned short* hact, const float* __restrict__ ss,
    const float* __restrict__ hw, const float* __restrict__ hb,
    float* __restrict__ out,
    int T, int rowGran, int RPB, int hstride, int head_off)
{
    __shared__ float headAcc[256];
    const int tid = threadIdx.x;
    headAcc[tid] = 0.f;
    __syncthreads();
    const int b0 = blockIdx.x * RPB;

    uint2 hv[GPT];
    #pragma unroll
    for (int j = 0; j < GPT; j++) {
        int G = tid + j * 256;
        int r = G / rowGran, gg = G % rowGran;
        hv[j] = *(const uint2*)(hact + (size_t)(b0 + r) * hstride + gg * 4);
    }
    #pragma unroll
    for (int j = 0; j < GPT; j++) {
        int G = tid + j * 256;
        int r = G / rowGran, gg = G % rowGran;
        int c = gg * 4;
        float4 sc = *(const float4*)(ss + c);
        float4 sh = *(const float4*)(ss + hstride + c);
        float4 w4 = *(const float4*)(hw + c);
        union { unsigned short u[4]; uint2 v; } iv, ov;
        iv.v = hv[j];
        float a0 = fast_tanh(bf2f(iv.u[0]) * sc.x + sh.x);
        float a1 = fast_tanh(bf2f(iv.u[1]) * sc.y + sh.y);
        float a2 = fast_tanh(bf2f(iv.u[2]) * sc.z + sh.z);
        float a3 = fast_tanh(bf2f(iv.u[3]) * sc.w + sh.w);
        ov.u[0] = f2bf(a0); ov.u[1] = f2bf(a1); ov.u[2] = f2bf(a2); ov.u[3] = f2bf(a3);
        *(uint2*)(hact + (size_t)(b0 + r) * hstride + c) = ov.v;
        float partial = a0 * w4.x + a1 * w4.y + a2 * w4.z + a3 * w4.w;
        int t = gg / 5;
        atomicAdd(&headAcc[r * T + t], partial);
    }
    __syncthreads();
    if (tid < RPB * T) {
        int r = tid / T, t = tid % T;
        out[(size_t)(b0 + r) * OUTW + head_off + t] = headAcc[tid] + hb[t];
    }
}

// ---- BN + tanh + strided act store + head — WAVE variant ----
__global__ __launch_bounds__(256) void bn_tanh_head(
    const unsigned short* __restrict__ h, const float* __restrict__ ss,
    const float* __restrict__ hw, const float* __restrict__ hb,
    unsigned short* __restrict__ actOut, float* __restrict__ out,
    int T, int O, int hstride, int aRow, int GT, int GS, int head_off, int TO)
{
    int wid  = (blockIdx.x * 256 + threadIdx.x) >> 6;
    int lane = threadIdx.x & 63;
    int b = wid / T;
    int t = wid % T;
    const size_t hbase = (size_t)b * hstride + (size_t)t * O;
    const size_t abase = (size_t)b * aRow + (size_t)(t / GT) * GS + (size_t)(t % GT) * O;
    float hsum = 0.f;
    for (int o = lane; o < O; o += 64) {
        int col = t * O + o;
        float a = fast_tanh(bf2f(h[hbase + o]) * ss[col] + ss[TO + col]);
        if (actOut) actOut[abase + o] = f2bf(a);
        hsum += a * hw[col];
    }
    #pragma unroll
    for (int off = 32; off > 0; off >>= 1) hsum += __shfl_down(hsum, off, 64);
    if (lane == 0) out[(size_t)b * OUTW + head_off + t] = hsum + hb[t];
}

extern "C" void kernel_launch(void* const* d_in, const int* in_sizes, int n_in,
                              void* d_out, int out_size, void* d_ws, size_t ws_size,
                              hipStream_t stream)
{
    const float* x = (const float*)d_in[0];
    float* out = (float*)d_out;
    char* ws = (char*)d_ws;

    // ws layout (bytes)
    unsigned short* wbt  = (unsigned short*)(ws);              // 13,762,560
    unsigned short* ain0 = (unsigned short*)(ws + 13762560);   // 22,020,096 (2048x5376)
    unsigned short* bufA = (unsigned short*)(ws + 35782656);   // 20,971,520
    unsigned short* bufB = (unsigned short*)(ws + 56754176);   //  5,242,880
    unsigned short* ain1 = (unsigned short*)(ws + 61997056);   // 22,020,096
    unsigned short* bufC = (unsigned short*)(ws + 84017152);   //  5,046,272
    float*          ss   = (float*)(ws + 89063424);            //     40,960
    float*          sp0  = (float*)(ws + 89104384);            //    157,312 (16x2x1229)
    // overlays (all dead at use time):
    float* partial = (float*)(ws + 35782656);   // s1: 21 MB (=bufA), s0: 41.9 MB
    float* sp4 = (float*)bufC;
    float* sp3 = (float*)bufC;
    float* sp2 = (float*)bufA;
    float* sp1 = (float*)bufB;
    unsigned short* xg = ain0 + 1232;           // full bf16 x copy, row stride 5376

    const float* W4 = (const float*)d_in[1];  const float* b4 = (const float*)d_in[2];
    const float* g4 = (const float*)d_in[3];  const float* bb4 = (const float*)d_in[4];
    const float* hw4 = (const float*)d_in[5]; const float* hb4 = (const float*)d_in[6];
    const float* W3 = (const float*)d_in[7];  const float* b3 = (const float*)d_in[8];
    const float* g3 = (const float*)d_in[9];  const float* bb3 = (const float*)d_in[10];
    const float* hw3 = (const float*)d_in[11]; const float* hb3 = (const float*)d_in[12];
    const float* W2 = (const float*)d_in[13]; const float* b2 = (const float*)d_in[14];
    const float* g2 = (const float*)d_in[15]; const float* bb2 = (const float*)d_in[16];
    const float* hw2 = (const float*)d_in[17]; const float* hb2 = (const float*)d_in[18];
    const float* W1 = (const float*)d_in[19]; const float* b1 = (const float*)d_in[20];
    const float* g1 = (const float*)d_in[21]; const float* bb1 = (const float*)d_in[22];
    const float* hw1 = (const float*)d_in[23]; const float* hb1 = (const float*)d_in[24];
    const float* W0 = (const float*)d_in[25]; const float* b0_ = (const float*)d_in[26];
    const float* g0 = (const float*)d_in[27]; const float* bb0 = (const float*)d_in[28];
    const float* hw0 = (const float*)d_in[29]; const float* hb0 = (const float*)d_in[30];

    // 1: pack + W4..W1 conversions
    prep<<<7184, 256, 0, stream>>>(x, ain0, ain1, W4, W3, W2, W1, wbt);

    // 2-4: s4 (T=256 I=16 O=20 Kpad=32, WbT @0)
    gemm_small<32, 32><<<dim3(1, 32, 256), 256, 0, stream>>>(
        nullptr, xg, wbt, b4, bufA, sp4, 256, 16, 20, 0, 16, 32, 5120, 5120);
    bn_scaleN<<<20, 256, 0, stream>>>(sp4, g4, bb4, ss, 5120, 32);
    bn_tanh_head_vec<5><<<BDIM, 256, 0, stream>>>(bufA, ss, hw4, hb4, out, 256, 1280, 1, 5120, 0);

    // 5-7: s3 (T=64 I=144 O=20 Kpad=192, WbT @163840)
    gemm_small<32, 64><<<dim3(1, 32, 64), 256, 0, stream>>>(
        bufA, xg, wbt + 163840, b3, bufB, sp3, 64, 144, 20, 80, 64, 192, 1280, 1280);
    bn_scaleN<<<5, 256, 0, stream>>>(sp3, g3, bb3, ss, 1280, 32);
    bn_tanh_head_vec<5><<<BDIM / 4, 256, 0, stream>>>(bufB, ss, hw3, hb3, out, 64, 320, 4, 1280, 256);

    // 8-10: s2 (T=16 I=336 O=77 Kpad=384, WbT @409600)
    gemm_small<64, 64><<<dim3(2, 32, 16), 256, 0, stream>>>(
        bufB, xg, wbt + 409600, b2, bufC, sp2, 16, 336, 77, 80, 256, 384, 1232, 1232);
    bn_scaleN<<<5, 256, 0, stream>>>(sp2, g2, bb2, ss, 1232, 32);
    bn_tanh_head<<<BDIM * 16 / 4, 256, 0, stream>>>(bufC, ss, hw2, hb2,
                                                    ain1, out, 16, 77, 1232, 5376, 4, 1344, 320, 1232);

    // 11-14: s1 (T=4 I=1332 O=308 Kpad=1344 Npad=320 KS=2, WbT @882688)
    gemm_split<64><<<640, 256, 0, stream>>>(ain1, wbt + 882688, partial,
                                            5376, 1344, 1344, 320, 2, 1280, 5, 8);
    reduce_stats_cvt<<<7040, 256, 0, stream>>>(partial, b1, bufC, sp1,
                                               4, 308, 320, 2, 1232, 1232, W0, wbt);
    bn_scaleN<<<5, 256, 0, stream>>>(sp1, g1, bb1, ss, 1232, 16);
    bn_tanh_head<<<BDIM * 4 / 4, 256, 0, stream>>>(bufC, ss, hw1, hb1,
                                                   ain0, out, 4, 308, 1232, 5376, 4, 0, 336, 1232);

    // 15-18: s0 (T=1 I=5328 O=1229 Kpad=5376 Npad=1280 KS=4)
    // BN=64: nTiles=20, TKS=4, grid = 8 * 8 * 20 = 1280 blocks (5/CU, was 2.5)
    gemm_split<64><<<1280, 256, 0, stream>>>(ain0, wbt, partial,
                                             5376, 0, 5376, 1280, 4, 1280, 20, 4);
    reduce_stats<<<320, 256, 0, stream>>>(partial, b0_, bufC, sp0,
                                          1, 1229, 1280, 4, 1232, 1229);
    bn_scaleN<<<5, 256, 0, stream>>>(sp0, g0, bb0, ss, 1229, 16);
    bn_tanh_head<<<BDIM / 4, 256, 0, stream>>>(bufC, ss, hw0, hb0,
                                               nullptr, out, 1, 1229, 1232, 1232, 1, 0, 340, 1229);
}